// Round 7
// baseline (581.359 us; speedup 1.0000x reference)
//
#include <hip/hip_runtime.h>

// RecurrentMambaCell: B=8192, D=2048, K=4, all fp32.
//   window   = concat(conv_state, x_t)            (B,D,4)
//   ncs      = window[:,:,1:]                     (B,D,3)
//   conv_out = sum_k window*W_conv[d,k] + b_conv  (B,D)
//   nss      = A*ssm + Bp*conv_out                (B,D)
//   y        = C*nss + D_skip*x                   (B,D)
// Pure streaming op: 320 MiB read + 320 MiB write => HBM-bound, ~106us floor.

constexpr int kB = 8192;
constexpr int kD = 2048;
constexpr long long kN = (long long)kB * kD;   // 16,777,216 elements

__global__ __launch_bounds__(256) void mamba_cell_kernel(
    const float* __restrict__ x_t,        // (B,D)
    const float* __restrict__ conv_state, // (B,D,3)
    const float* __restrict__ ssm_state,  // (B,D)
    const float* __restrict__ W_conv,     // (D,4)
    const float* __restrict__ b_conv,     // (D,)
    const float* __restrict__ A,          // (D,)
    const float* __restrict__ Bp,         // (D,)
    const float* __restrict__ C,          // (D,)
    const float* __restrict__ D_skip,     // (D,)
    float* __restrict__ y_out,            // (B,D)
    float* __restrict__ ncs_out,          // (B,D,3)
    float* __restrict__ nss_out)          // (B,D)
{
    const long long ngroups = kN / 4;     // 4 elements (one float4) per group
    long long g = (long long)blockIdx.x * blockDim.x + threadIdx.x;
    const long long gstride = (long long)gridDim.x * blockDim.x;

    for (; g < ngroups; g += gstride) {
        const long long i = g * 4;            // element index of lane 0 of group
        const int d0 = (int)(i & (kD - 1));   // D is a power of two; d0 % 4 == 0

        // --- loads (all 16B-aligned float4) ---
        const float4 x  = *(const float4*)(x_t + i);
        const float4 s  = *(const float4*)(ssm_state + i);
        const float4 c0 = *(const float4*)(conv_state + 3 * i);      // e0k0 e0k1 e0k2 e1k0
        const float4 c1 = *(const float4*)(conv_state + 3 * i + 4);  // e1k1 e1k2 e2k0 e2k1
        const float4 c2 = *(const float4*)(conv_state + 3 * i + 8);  // e2k2 e3k0 e3k1 e3k2

        const float4 w0 = *(const float4*)(W_conv + (long long)(d0 + 0) * 4);
        const float4 w1 = *(const float4*)(W_conv + (long long)(d0 + 1) * 4);
        const float4 w2 = *(const float4*)(W_conv + (long long)(d0 + 2) * 4);
        const float4 w3 = *(const float4*)(W_conv + (long long)(d0 + 3) * 4);
        const float4 bc = *(const float4*)(b_conv + d0);
        const float4 a  = *(const float4*)(A + d0);
        const float4 bp = *(const float4*)(Bp + d0);
        const float4 cc = *(const float4*)(C + d0);
        const float4 ds = *(const float4*)(D_skip + d0);

        // --- conv_out = window . W_conv + b_conv (K=4, last tap is x) ---
        const float co0 = c0.x * w0.x + c0.y * w0.y + c0.z * w0.z + x.x * w0.w + bc.x;
        const float co1 = c0.w * w1.x + c1.x * w1.y + c1.y * w1.z + x.y * w1.w + bc.y;
        const float co2 = c1.z * w2.x + c1.w * w2.y + c2.x * w2.z + x.z * w2.w + bc.z;
        const float co3 = c2.y * w3.x + c2.z * w3.y + c2.w * w3.z + x.w * w3.w + bc.w;

        // --- SSM update + output ---
        float4 ns;
        ns.x = a.x * s.x + bp.x * co0;
        ns.y = a.y * s.y + bp.y * co1;
        ns.z = a.z * s.z + bp.z * co2;
        ns.w = a.w * s.w + bp.w * co3;

        float4 y;
        y.x = cc.x * ns.x + ds.x * x.x;
        y.y = cc.y * ns.y + ds.y * x.y;
        y.z = cc.z * ns.z + ds.z * x.z;
        y.w = cc.w * ns.w + ds.w * x.w;

        // --- new conv state: per element (k1, k2, x) ---
        float4 o0, o1, o2;
        o0.x = c0.y; o0.y = c0.z; o0.z = x.x; o0.w = c1.x;   // e0k1 e0k2 x0 | e1k1
        o1.x = c1.y; o1.y = x.y;  o1.z = c1.w; o1.w = c2.x;  // e1k2 x1 | e2k1 e2k2
        o2.x = x.z;  o2.y = c2.z; o2.z = c2.w; o2.w = x.w;   // x2 | e3k1 e3k2 x3

        // --- stores (all 16B-aligned float4) ---
        *(float4*)(y_out + i)           = y;
        *(float4*)(nss_out + i)         = ns;
        *(float4*)(ncs_out + 3 * i)     = o0;
        *(float4*)(ncs_out + 3 * i + 4) = o1;
        *(float4*)(ncs_out + 3 * i + 8) = o2;
    }
}

extern "C" void kernel_launch(void* const* d_in, const int* in_sizes, int n_in,
                              void* d_out, int out_size, void* d_ws, size_t ws_size,
                              hipStream_t stream) {
    const float* x_t        = (const float*)d_in[0];
    const float* conv_state = (const float*)d_in[1];
    const float* ssm_state  = (const float*)d_in[2];
    const float* W_conv     = (const float*)d_in[3];
    const float* b_conv     = (const float*)d_in[4];
    const float* A          = (const float*)d_in[5];
    const float* Bp         = (const float*)d_in[6];
    const float* C          = (const float*)d_in[7];
    const float* D_skip     = (const float*)d_in[8];

    // d_out layout: y_t (N) | new_conv_state (3N) | new_ssm_state (N)
    float* y_out   = (float*)d_out;
    float* ncs_out = y_out + kN;
    float* nss_out = y_out + 4 * kN;

    // Memory-bound: cap grid and grid-stride (256 CUs x 8 blocks/CU = 2048).
    const int block = 256;
    const int grid  = 2048;
    mamba_cell_kernel<<<grid, block, 0, stream>>>(
        x_t, conv_state, ssm_state, W_conv, b_conv, A, Bp, C, D_skip,
        y_out, ncs_out, nss_out);
}